// Round 2
// baseline (745.012 us; speedup 1.0000x reference)
//
#include <hip/hip_runtime.h>

typedef __bf16 bf16;
typedef __bf16 bf16x4 __attribute__((ext_vector_type(4)));
typedef __bf16 bf16x8 __attribute__((ext_vector_type(8)));
typedef float f32x4 __attribute__((ext_vector_type(4)));

#define LOG2E 1.4426950408889634f

// ---------------------------------------------------------------------------
// Projection: Out = X @ W^T + bias.  X:[4096,1024] f32, W:[1024,1024] f32.
// z=0 -> Q' (bf16, [4096,1024]), z=1 -> K' (same), z=2 -> V'^T per head:
//   vt[(b*1024 + n)*2048 + s]   (n = h*64+d), so attention can read V^T rows
//   with contiguous s (kk) for the MFMA B-operand layout.
// ---------------------------------------------------------------------------
__global__ __launch_bounds__(256, 2)
void proj_kernel(const float* __restrict__ Xq, const float* __restrict__ Xk,
                 const float* __restrict__ Xv,
                 const float* __restrict__ Wq, const float* __restrict__ Wk,
                 const float* __restrict__ Wv,
                 const float* __restrict__ Bq, const float* __restrict__ Bk,
                 const float* __restrict__ Bv,
                 bf16* __restrict__ Oq, bf16* __restrict__ Ok,
                 bf16* __restrict__ Ov)
{
    const int z = blockIdx.z;
    const float* X  = (z == 0) ? Xq : (z == 1) ? Xk : Xv;
    const float* W  = (z == 0) ? Wq : (z == 1) ? Wk : Wv;
    const float* Bi = (z == 0) ? Bq : (z == 1) ? Bk : Bv;

    const int n0 = blockIdx.x * 128;
    const int m0 = blockIdx.y * 128;

    __shared__ bf16 As[128 * 40];
    __shared__ bf16 Bs[128 * 40];

    const int t = threadIdx.x;
    const int w = t >> 6, l = t & 63, quad = l >> 4, ln = l & 15;
    const int wm = (w & 1) * 64, wn = (w >> 1) * 64;

    const f32x4 zero4 = {0.f, 0.f, 0.f, 0.f};
    f32x4 acc[4][4];
    for (int mi = 0; mi < 4; mi++)
        for (int ni = 0; ni < 4; ni++) acc[mi][ni] = zero4;

    for (int k0 = 0; k0 < 1024; k0 += 32) {
        for (int i = 0; i < 4; i++) {
            int idx = i * 256 + t;
            int row = idx >> 3, c4 = idx & 7;
            float4 a  = *(const float4*)&X[(size_t)(m0 + row) * 1024 + k0 + c4 * 4];
            float4 bb = *(const float4*)&W[(size_t)(n0 + row) * 1024 + k0 + c4 * 4];
            bf16x4 av, bv;
            av[0] = (bf16)a.x;  av[1] = (bf16)a.y;  av[2] = (bf16)a.z;  av[3] = (bf16)a.w;
            bv[0] = (bf16)bb.x; bv[1] = (bf16)bb.y; bv[2] = (bf16)bb.z; bv[3] = (bf16)bb.w;
            *(bf16x4*)&As[row * 40 + c4 * 4] = av;
            *(bf16x4*)&Bs[row * 40 + c4 * 4] = bv;
        }
        __syncthreads();

        bf16x8 af[4], bfv[4];
        for (int mi = 0; mi < 4; mi++)
            af[mi] = *(const bf16x8*)&As[(wm + mi * 16 + ln) * 40 + quad * 8];
        for (int ni = 0; ni < 4; ni++)
            bfv[ni] = *(const bf16x8*)&Bs[(wn + ni * 16 + ln) * 40 + quad * 8];
        for (int mi = 0; mi < 4; mi++)
            for (int ni = 0; ni < 4; ni++)
                acc[mi][ni] = __builtin_amdgcn_mfma_f32_16x16x32_bf16(
                    af[mi], bfv[ni], acc[mi][ni], 0, 0, 0);
        __syncthreads();
    }

    bf16* Onat = (z == 0) ? Oq : Ok;
    for (int ni = 0; ni < 4; ni++) {
        int n = n0 + wn + ni * 16 + ln;
        float bias = Bi[n];
        for (int mi = 0; mi < 4; mi++) {
            int mbase = m0 + wm + mi * 16 + quad * 4;
            if (z < 2) {
                for (int r = 0; r < 4; r++)
                    Onat[(size_t)(mbase + r) * 1024 + n] = (bf16)(acc[mi][ni][r] + bias);
            } else {
                int b = mbase >> 11, s0 = mbase & 2047;
                bf16x4 vv;
                for (int r = 0; r < 4; r++) vv[r] = (bf16)(acc[mi][ni][r] + bias);
                *(bf16x4*)&Ov[(size_t)(b * 1024 + n) * 2048 + s0] = vv;
            }
        }
    }
}

// ---------------------------------------------------------------------------
// Fused flash attention, occupancy-first restructure:
//   - q-tile 64 (wave owns 16 q rows) -> 1024 blocks, 4 blocks/CU (16 waves/CU)
//   - LDS: K double-buffered (2x9KB) + wave-private Ps (9KB) = 27.6KB
//   - Q fragments loaded once direct from global; V^T fragments read direct
//     from global each tile (L2-resident; reused 32x per (b,h) on one XCD)
//   - ONE __syncthreads per k-tile: ds_read K frags -> prefetch next K tile
//     to regs -> compute (QK^T, nt-store scores early, softmax, PV) ->
//     ds_write next tile -> barrier.  Prefetch + store latency hidden
//     under compute; only one vmcnt drain point per iteration.
//   - transposed score tile (ST = K Q^T): thread's 4 acc regs = 4 consecutive
//     kk for one fixed q => scalar softmax state, 2 shuffles per reduction,
//     dwordx4 score stores.
// ---------------------------------------------------------------------------
__global__ __launch_bounds__(256, 4)
void attn_kernel(const bf16* __restrict__ Qp, const bf16* __restrict__ Kp,
                 const bf16* __restrict__ Vt, const float* __restrict__ mask,
                 float* __restrict__ ctx, float* __restrict__ scores)
{
    // XCD-chunked bijective swizzle: 1024 blocks, 8 XCDs, 128 per XCD.
    // All 32 q-tiles of a (b,h) pair land on one XCD -> K/V L2 reuse.
    const int lid = blockIdx.x;
    const int wg  = (lid & 7) * 128 + (lid >> 3);
    const int qt = wg & 31, h = (wg >> 5) & 15, b = wg >> 9;

    const int q0 = qt * 64;
    const int t = threadIdx.x, w = t >> 6, l = t & 63, quad = l >> 4, ln = l & 15;

    __shared__ bf16 Ks[2][64 * 72];   // [kk][d] ld=72, double-buffered
    __shared__ bf16 Ps[64 * 72];      // [q][kk] ld=72, wave-private rows

    // thread's fixed q row (MFMA B-operand n = ln)
    const int qrow = q0 + w * 16 + ln;

    // Q fragments direct from global, held all kernel
    bf16x8 qf[2];
#pragma unroll
    for (int ks = 0; ks < 2; ks++)
        qf[ks] = *(const bf16x8*)&Qp[(size_t)(b * 2048 + qrow) * 1024 + h * 64 + ks * 32 + quad * 8];

    // K staging map: thread t copies 32B of row krow
    const int krow = t >> 2, kseg = t & 3;
    const bf16* kbase = &Kp[(size_t)(b * 2048 + krow) * 1024 + h * 64 + kseg * 16];

    // prologue: stage K tile 0
    {
        bf16x8 r0 = *(const bf16x8*)&kbase[0];
        bf16x8 r1 = *(const bf16x8*)&kbase[8];
        *(bf16x8*)&Ks[0][krow * 72 + kseg * 16 + 0] = r0;
        *(bf16x8*)&Ks[0][krow * 72 + kseg * 16 + 8] = r1;
    }
    __syncthreads();

    const f32x4 zero4 = {0.f, 0.f, 0.f, 0.f};
    f32x4 Ot[4];                       // O^T: [d-frag ni], col = q (fixed per thread)
#pragma unroll
    for (int ni = 0; ni < 4; ni++) Ot[ni] = zero4;
    float mst = -1e30f, lst = 0.f;

    const size_t srow = ((size_t)((b * 16 + h) * 2048 + qrow)) * 2048;
    const bf16* vbase = &Vt[(size_t)(b * 1024 + h * 64) * 2048];

    for (int kt = 0; kt < 32; kt++) {
        const int kk0 = kt * 64;
        const int cur = kt & 1;

        // prefetch next K tile into regs (latency hidden under compute)
        bf16x8 pr0, pr1;
        if (kt < 31) {
            const bf16* src = kbase + (size_t)(kk0 + 64) * 1024;
            pr0 = *(const bf16x8*)&src[0];
            pr1 = *(const bf16x8*)&src[8];
        }

        // ST = K Q^T : row(m)=kk=16*ni+quad*4+r, col(n)=q=ln
        f32x4 st[4];
#pragma unroll
        for (int ni = 0; ni < 4; ni++) st[ni] = zero4;
#pragma unroll
        for (int ks = 0; ks < 2; ks++) {
            bf16x8 kf[4];
#pragma unroll
            for (int ni = 0; ni < 4; ni++)
                kf[ni] = *(const bf16x8*)&Ks[cur][(ni * 16 + ln) * 72 + ks * 32 + quad * 8];
#pragma unroll
            for (int ni = 0; ni < 4; ni++)
                st[ni] = __builtin_amdgcn_mfma_f32_16x16x32_bf16(
                    kf[ni], qf[ks], st[ni], 0, 0, 0);
        }

        // mask (uniform over ln; 4 consecutive kk per ni)
        f32x4 mv[4];
#pragma unroll
        for (int ni = 0; ni < 4; ni++)
            mv[ni] = *(const f32x4*)&mask[b * 2048 + kk0 + ni * 16 + quad * 4];

        // scale + mask + stream raw scores early (nontemporal dwordx4)
#pragma unroll
        for (int ni = 0; ni < 4; ni++) {
            f32x4 v = st[ni];
#pragma unroll
            for (int r = 0; r < 4; r++) v[r] = v[r] * 0.125f + mv[ni][r];
            st[ni] = v;
            __builtin_nontemporal_store(v, (f32x4*)&scores[srow + kk0 + ni * 16 + quad * 4]);
        }

        // online softmax for this thread's q row
        float rm = -1e30f;
#pragma unroll
        for (int ni = 0; ni < 4; ni++)
#pragma unroll
            for (int r = 0; r < 4; r++) rm = fmaxf(rm, st[ni][r]);
        rm = fmaxf(rm, __shfl_xor(rm, 16));
        rm = fmaxf(rm, __shfl_xor(rm, 32));
        const float mnew  = fmaxf(mst, rm);
        const float alpha = exp2f((mst - mnew) * LOG2E);
        mst = mnew;

        float rs = 0.f;
#pragma unroll
        for (int ni = 0; ni < 4; ni++) {
            bf16x4 pv;
#pragma unroll
            for (int r = 0; r < 4; r++) {
                float p = exp2f((st[ni][r] - mnew) * LOG2E);
                rs += p;
                pv[r] = (bf16)p;
            }
            // P[q][kk]: 4 contiguous kk -> single ds_write_b64 (wave-private row)
            *(bf16x4*)&Ps[(w * 16 + ln) * 72 + ni * 16 + quad * 4] = pv;
        }
        rs += __shfl_xor(rs, 16);
        rs += __shfl_xor(rs, 32);
        lst = lst * alpha + rs;

#pragma unroll
        for (int ni = 0; ni < 4; ni++)
#pragma unroll
            for (int r = 0; r < 4; r++) Ot[ni][r] *= alpha;

        // O^T += V^T P^T  (A: m=d from global V^T; B: n=q from Ps)
#pragma unroll
        for (int ks = 0; ks < 2; ks++) {
            bf16x8 vf[4];
#pragma unroll
            for (int ni = 0; ni < 4; ni++)
                vf[ni] = *(const bf16x8*)&vbase[(size_t)(ni * 16 + ln) * 2048 + kk0 + ks * 32 + quad * 8];
            bf16x8 pf = *(const bf16x8*)&Ps[(w * 16 + ln) * 72 + ks * 32 + quad * 8];
#pragma unroll
            for (int ni = 0; ni < 4; ni++)
                Ot[ni] = __builtin_amdgcn_mfma_f32_16x16x32_bf16(
                    vf[ni], pf, Ot[ni], 0, 0, 0);
        }

        // stage next K tile; single barrier per iteration
        if (kt < 31) {
            *(bf16x8*)&Ks[cur ^ 1][krow * 72 + kseg * 16 + 0] = pr0;
            *(bf16x8*)&Ks[cur ^ 1][krow * 72 + kseg * 16 + 8] = pr1;
            __syncthreads();
        }
    }

    // epilogue: ctx[q][d] = O^T / l  (4 consecutive d per thread = dwordx4)
    const float rl = 1.0f / lst;
#pragma unroll
    for (int ni = 0; ni < 4; ni++) {
        f32x4 o = Ot[ni];
#pragma unroll
        for (int r = 0; r < 4; r++) o[r] *= rl;
        *(f32x4*)&ctx[(size_t)(b * 2048 + qrow) * 1024 + h * 64 + ni * 16 + quad * 4] = o;
    }
}

extern "C" void kernel_launch(void* const* d_in, const int* in_sizes, int n_in,
                              void* d_out, int out_size, void* d_ws, size_t ws_size,
                              hipStream_t stream) {
    const float* q    = (const float*)d_in[0];
    const float* k    = (const float*)d_in[1];
    const float* v    = (const float*)d_in[2];
    const float* mask = (const float*)d_in[3];
    const float* Wq   = (const float*)d_in[4];
    const float* bq   = (const float*)d_in[5];
    const float* Wk   = (const float*)d_in[6];
    const float* bk   = (const float*)d_in[7];
    const float* Wv   = (const float*)d_in[8];
    const float* bv   = (const float*)d_in[9];

    bf16* Qp = (bf16*)d_ws;                 // [4096,1024]
    bf16* Kp = Qp + (size_t)4096 * 1024;    // [4096,1024]
    bf16* Vt = Kp + (size_t)4096 * 1024;    // [B*1024, 2048] = V'^T per head

    float* ctx    = (float*)d_out;                    // [2,2048,1024]
    float* scores = ctx + (size_t)2 * 2048 * 1024;    // [2,16,2048,2048]

    proj_kernel<<<dim3(8, 32, 3), 256, 0, stream>>>(
        q, k, v, Wq, Wk, Wv, bq, bk, bv, Qp, Kp, Vt);
    attn_kernel<<<dim3(1024, 1, 1), 256, 0, stream>>>(
        Qp, Kp, Vt, mask, ctx, scores);
}

// Round 4
// 737.047 us; speedup vs baseline: 1.0108x; 1.0108x over previous
//
#include <hip/hip_runtime.h>

typedef __bf16 bf16;
typedef __bf16 bf16x4 __attribute__((ext_vector_type(4)));
typedef __bf16 bf16x8 __attribute__((ext_vector_type(8)));
typedef float f32x4 __attribute__((ext_vector_type(4)));

#define LOG2E 1.4426950408889634f

#define GLOAD_LDS(gptr, lptr)                                                   \
    __builtin_amdgcn_global_load_lds(                                           \
        (const __attribute__((address_space(1))) void*)(gptr),                  \
        (__attribute__((address_space(3))) void*)(lptr), 16, 0, 0)

// ---------------------------------------------------------------------------
// One-shot f32 -> bf16 conversion of the 6 proj inputs.
// grid dim3(1024, 6); z = {q,k,v,Wq,Wk,Wv}. Each block converts 4096 floats.
// Outputs live in the TAIL of the scores output region (scratch): attn_kernel
// overwrites all of scores strictly after proj_kernel consumed the scratch
// (same-stream serialization), and d_ws stays at the 24 MB that passed.
// ---------------------------------------------------------------------------
__global__ __launch_bounds__(256)
void cvt_kernel(const float* __restrict__ q, const float* __restrict__ k,
                const float* __restrict__ v, const float* __restrict__ wq,
                const float* __restrict__ wk, const float* __restrict__ wv,
                bf16* __restrict__ xq, bf16* __restrict__ xk,
                bf16* __restrict__ xv, bf16* __restrict__ wqb,
                bf16* __restrict__ wkb, bf16* __restrict__ wvb)
{
    const int z = blockIdx.y;
    if (z >= 3 && blockIdx.x >= 256) return;   // W matrices are 1M elems
    const float* src = (z == 0) ? q : (z == 1) ? k : (z == 2) ? v
                     : (z == 3) ? wq : (z == 4) ? wk : wv;
    bf16* dst = (z == 0) ? xq : (z == 1) ? xk : (z == 2) ? xv
              : (z == 3) ? wqb : (z == 4) ? wkb : wvb;
    const size_t base = (size_t)blockIdx.x * 4096 + threadIdx.x * 4;
#pragma unroll
    for (int p = 0; p < 4; p++) {
        float4 a = *(const float4*)&src[base + p * 1024];
        bf16x4 o;
        o[0] = (bf16)a.x; o[1] = (bf16)a.y; o[2] = (bf16)a.z; o[3] = (bf16)a.w;
        *(bf16x4*)&dst[base + p * 1024] = o;
    }
}

// ---------------------------------------------------------------------------
// Projection: Out = X @ W^T + bias.  X:[4096,1024] bf16, W:[1024,1024] bf16.
// m97-style staging: global_load_lds width=16 direct HBM->LDS, LDS organized
// FRAGMENT-MAJOR: 8 frags x 1KB per matrix; frag fr holds rows
// [fr*16, fr*16+16) with lane l = quad*16+ln owning A[fr*16+ln][quad*8..+8].
//   - global_load_lds dest = wave-uniform base + lane*16 -> exactly frag order
//   - ds_read_b128 of a frag is CONTIGUOUS 1KB per wave -> 0 bank conflicts
// z=0 -> Q' (bf16, [4096,1024]), z=1 -> K' (same), z=2 -> V'^T per head:
//   vt[(b*1024 + n)*2048 + s]   (n = h*64+d).
// ---------------------------------------------------------------------------
__global__ __launch_bounds__(256, 2)
void proj_kernel(const bf16* __restrict__ Xq, const bf16* __restrict__ Xk,
                 const bf16* __restrict__ Xv,
                 const bf16* __restrict__ Wq, const bf16* __restrict__ Wk,
                 const bf16* __restrict__ Wv,
                 const float* __restrict__ Bq, const float* __restrict__ Bk,
                 const float* __restrict__ Bv,
                 bf16* __restrict__ Oq, bf16* __restrict__ Ok,
                 bf16* __restrict__ Ov)
{
    const int z = blockIdx.z;
    const bf16* X  = (z == 0) ? Xq : (z == 1) ? Xk : Xv;
    const bf16* W  = (z == 0) ? Wq : (z == 1) ? Wk : Wv;
    const float* Bi = (z == 0) ? Bq : (z == 1) ? Bk : Bv;

    const int n0 = blockIdx.x * 128;
    const int m0 = blockIdx.y * 128;

    __shared__ bf16 As[8 * 512];   // 8 fragments x 1KB, fragment-major
    __shared__ bf16 Bs[8 * 512];

    const int t = threadIdx.x;
    const int w = t >> 6, l = t & 63, quad = l >> 4, ln = l & 15;

    // this wave stages frags {2w, 2w+1} of both matrices
    const int fa0 = w * 2, fa1 = w * 2 + 1;
    const bf16* gA0 = &X[(size_t)(m0 + fa0 * 16 + ln) * 1024 + quad * 8];
    const bf16* gA1 = &X[(size_t)(m0 + fa1 * 16 + ln) * 1024 + quad * 8];
    const bf16* gB0 = &W[(size_t)(n0 + fa0 * 16 + ln) * 1024 + quad * 8];
    const bf16* gB1 = &W[(size_t)(n0 + fa1 * 16 + ln) * 1024 + quad * 8];

    const f32x4 zero4 = {0.f, 0.f, 0.f, 0.f};
    f32x4 acc[4][4];
    for (int mi = 0; mi < 4; mi++)
        for (int ni = 0; ni < 4; ni++) acc[mi][ni] = zero4;

    const int wafr = (w & 1) * 4;    // A frags this wave consumes
    const int wbfr = (w >> 1) * 4;   // B frags this wave consumes

    for (int k0 = 0; k0 < 1024; k0 += 32) {
        GLOAD_LDS(gA0 + k0, &As[fa0 * 512]);
        GLOAD_LDS(gA1 + k0, &As[fa1 * 512]);
        GLOAD_LDS(gB0 + k0, &Bs[fa0 * 512]);
        GLOAD_LDS(gB1 + k0, &Bs[fa1 * 512]);
        __syncthreads();   // drains vmcnt(0): LDS tiles complete

        bf16x8 af[4], bfv[4];
#pragma unroll
        for (int mi = 0; mi < 4; mi++)
            af[mi] = *(const bf16x8*)&As[(wafr + mi) * 512 + l * 8];
#pragma unroll
        for (int ni = 0; ni < 4; ni++)
            bfv[ni] = *(const bf16x8*)&Bs[(wbfr + ni) * 512 + l * 8];
#pragma unroll
        for (int mi = 0; mi < 4; mi++)
#pragma unroll
            for (int ni = 0; ni < 4; ni++)
                acc[mi][ni] = __builtin_amdgcn_mfma_f32_16x16x32_bf16(
                    af[mi], bfv[ni], acc[mi][ni], 0, 0, 0);
        __syncthreads();   // all reads done before next stage overwrites
    }

    // epilogue: C/D layout col = ln, row = quad*4 + r
    const int wm = (w & 1) * 64, wn = (w >> 1) * 64;
    bf16* Onat = (z == 0) ? Oq : Ok;
    for (int ni = 0; ni < 4; ni++) {
        int n = n0 + wn + ni * 16 + ln;
        float bias = Bi[n];
        for (int mi = 0; mi < 4; mi++) {
            int mbase = m0 + wm + mi * 16 + quad * 4;
            if (z < 2) {
                for (int r = 0; r < 4; r++)
                    Onat[(size_t)(mbase + r) * 1024 + n] = (bf16)(acc[mi][ni][r] + bias);
            } else {
                int b = mbase >> 11, s0 = mbase & 2047;
                bf16x4 vv;
                for (int r = 0; r < 4; r++) vv[r] = (bf16)(acc[mi][ni][r] + bias);
                *(bf16x4*)&Ov[(size_t)(b * 1024 + n) * 2048 + s0] = vv;
            }
        }
    }
}

// ---------------------------------------------------------------------------
// Fused flash attention (round-1 version, best measured): transposed score
// tile ST = K Q^T; scores streamed as nontemporal dwordx4; P via ds_write_b64;
// scalar softmax state; O accumulated transposed; XCD-chunked block swizzle.
// ---------------------------------------------------------------------------
__global__ __launch_bounds__(256, 2)
void attn_kernel(const bf16* __restrict__ Qp, const bf16* __restrict__ Kp,
                 const bf16* __restrict__ Vt, const float* __restrict__ mask,
                 float* __restrict__ ctx, float* __restrict__ scores)
{
    const int lid = blockIdx.x;
    const int wg  = (lid & 7) * 64 + (lid >> 3);
    const int qt = wg & 15, h = (wg >> 4) & 15, b = wg >> 8;

    const int q0 = qt * 128;
    const int t = threadIdx.x, w = t >> 6, l = t & 63, quad = l >> 4, ln = l & 15;

    __shared__ bf16 Qs[128 * 72];
    __shared__ bf16 Ks[64 * 72];
    __shared__ bf16 VTs[64 * 72];
    __shared__ bf16 Ps[128 * 72];

    for (int i = 0; i < 4; i++) {
        int idx = i * 256 + t;
        int row = idx >> 3, d8 = idx & 7;
        *(bf16x8*)&Qs[row * 72 + d8 * 8] =
            *(const bf16x8*)&Qp[(size_t)(b * 2048 + q0 + row) * 1024 + h * 64 + d8 * 8];
    }
    __syncthreads();

    bf16x8 qf[2][2];
#pragma unroll
    for (int mi = 0; mi < 2; mi++)
#pragma unroll
        for (int ks = 0; ks < 2; ks++)
            qf[mi][ks] = *(const bf16x8*)&Qs[(w * 32 + mi * 16 + ln) * 72 + ks * 32 + quad * 8];

    const f32x4 zero4 = {0.f, 0.f, 0.f, 0.f};
    f32x4 Ot[4][2];
#pragma unroll
    for (int ni = 0; ni < 4; ni++)
#pragma unroll
        for (int mi = 0; mi < 2; mi++) Ot[ni][mi] = zero4;
    float mst[2] = {-1e30f, -1e30f};
    float lst[2] = {0.f, 0.f};

    for (int kt = 0; kt < 32; kt++) {
        const int kk0 = kt * 64;
        __syncthreads();
        for (int i = 0; i < 2; i++) {
            int idx = i * 256 + t;
            int row = idx >> 3, d8 = idx & 7;
            *(bf16x8*)&Ks[row * 72 + d8 * 8] =
                *(const bf16x8*)&Kp[(size_t)(b * 2048 + kk0 + row) * 1024 + h * 64 + d8 * 8];
            *(bf16x8*)&VTs[row * 72 + d8 * 8] =
                *(const bf16x8*)&Vt[(size_t)(b * 1024 + h * 64 + row) * 2048 + kk0 + d8 * 8];
        }
        __syncthreads();

        f32x4 st[4][2];
#pragma unroll
        for (int ni = 0; ni < 4; ni++)
#pragma unroll
            for (int mi = 0; mi < 2; mi++) st[ni][mi] = zero4;
#pragma unroll
        for (int ks = 0; ks < 2; ks++) {
            bf16x8 kf[4];
#pragma unroll
            for (int ni = 0; ni < 4; ni++)
                kf[ni] = *(const bf16x8*)&Ks[(ni * 16 + ln) * 72 + ks * 32 + quad * 8];
#pragma unroll
            for (int ni = 0; ni < 4; ni++)
#pragma unroll
                for (int mi = 0; mi < 2; mi++)
                    st[ni][mi] = __builtin_amdgcn_mfma_f32_16x16x32_bf16(
                        kf[ni], qf[mi][ks], st[ni][mi], 0, 0, 0);
        }

        f32x4 mv[4];
#pragma unroll
        for (int ni = 0; ni < 4; ni++)
            mv[ni] = *(const f32x4*)&mask[b * 2048 + kk0 + ni * 16 + quad * 4];

#pragma unroll
        for (int mi = 0; mi < 2; mi++) {
            const size_t srow =
                ((size_t)((b * 16 + h) * 2048 + q0 + w * 32 + mi * 16 + ln)) * 2048 + kk0;
#pragma unroll
            for (int ni = 0; ni < 4; ni++) {
                f32x4 v = st[ni][mi];
#pragma unroll
                for (int r = 0; r < 4; r++) v[r] = v[r] * 0.125f + mv[ni][r];
                st[ni][mi] = v;
                __builtin_nontemporal_store(
                    v, (f32x4*)&scores[srow + ni * 16 + quad * 4]);
            }
        }

#pragma unroll
        for (int mi = 0; mi < 2; mi++) {
            float rm = -1e30f;
#pragma unroll
            for (int ni = 0; ni < 4; ni++)
#pragma unroll
                for (int r = 0; r < 4; r++) rm = fmaxf(rm, st[ni][mi][r]);
            rm = fmaxf(rm, __shfl_xor(rm, 16));
            rm = fmaxf(rm, __shfl_xor(rm, 32));
            const float mnew  = fmaxf(mst[mi], rm);
            const float alpha = exp2f((mst[mi] - mnew) * LOG2E);
            mst[mi] = mnew;

            float rs = 0.f;
#pragma unroll
            for (int ni = 0; ni < 4; ni++) {
                bf16x4 pv;
#pragma unroll
                for (int r = 0; r < 4; r++) {
                    float p = exp2f((st[ni][mi][r] - mnew) * LOG2E);
                    rs += p;
                    pv[r] = (bf16)p;
                }
                *(bf16x4*)&Ps[(w * 32 + mi * 16 + ln) * 72 + ni * 16 + quad * 4] = pv;
            }
            rs += __shfl_xor(rs, 16);
            rs += __shfl_xor(rs, 32);
            lst[mi] = lst[mi] * alpha + rs;

#pragma unroll
            for (int ni = 0; ni < 4; ni++)
#pragma unroll
                for (int r = 0; r < 4; r++) Ot[ni][mi][r] *= alpha;
        }

#pragma unroll
        for (int ks = 0; ks < 2; ks++) {
            bf16x8 vf[4], pf[2];
#pragma unroll
            for (int ni = 0; ni < 4; ni++)
                vf[ni] = *(const bf16x8*)&VTs[(ni * 16 + ln) * 72 + ks * 32 + quad * 8];
#pragma unroll
            for (int mi = 0; mi < 2; mi++)
                pf[mi] = *(const bf16x8*)&Ps[(w * 32 + mi * 16 + ln) * 72 + ks * 32 + quad * 8];
#pragma unroll
            for (int ni = 0; ni < 4; ni++)
#pragma unroll
                for (int mi = 0; mi < 2; mi++)
                    Ot[ni][mi] = __builtin_amdgcn_mfma_f32_16x16x32_bf16(
                        vf[ni], pf[mi], Ot[ni][mi], 0, 0, 0);
        }
    }

#pragma unroll
    for (int mi = 0; mi < 2; mi++) {
        const float rl = 1.0f / lst[mi];
        const int row = b * 2048 + q0 + w * 32 + mi * 16 + ln;
#pragma unroll
        for (int ni = 0; ni < 4; ni++) {
            f32x4 o = Ot[ni][mi];
#pragma unroll
            for (int r = 0; r < 4; r++) o[r] *= rl;
            *(f32x4*)&ctx[(size_t)row * 1024 + h * 64 + ni * 16 + quad * 4] = o;
        }
    }
}

extern "C" void kernel_launch(void* const* d_in, const int* in_sizes, int n_in,
                              void* d_out, int out_size, void* d_ws, size_t ws_size,
                              hipStream_t stream) {
    const float* q    = (const float*)d_in[0];
    const float* k    = (const float*)d_in[1];
    const float* v    = (const float*)d_in[2];
    const float* mask = (const float*)d_in[3];
    const float* Wq   = (const float*)d_in[4];
    const float* bq   = (const float*)d_in[5];
    const float* Wk   = (const float*)d_in[6];
    const float* bk   = (const float*)d_in[7];
    const float* Wv   = (const float*)d_in[8];
    const float* bv   = (const float*)d_in[9];

    // d_ws: exactly the 24 MB footprint that passed in rounds 0-2.
    bf16* Qp  = (bf16*)d_ws;                  // [4096,1024]
    bf16* Kp  = Qp  + (size_t)4096 * 1024;    // [4096,1024]
    bf16* Vt  = Kp  + (size_t)4096 * 1024;    // [B*1024, 2048]

    float* ctx    = (float*)d_out;                    // [2,2048,1024]
    float* scores = ctx + (size_t)2 * 2048 * 1024;    // [2,16,2048,2048]

    // bf16 scratch in the TAIL of scores (last 30 MB of 512 MB):
    // written by cvt, read by proj, then fully overwritten by attn.
    // 536870912 B total; scratch = 31457280 B -> starts at float index
    // (536870912 - 31457280)/4 = 126353408.
    bf16* Xbq = (bf16*)(scores + 126353408);
    bf16* Xbk = Xbq + (size_t)4096 * 1024;
    bf16* Xbv = Xbk + (size_t)4096 * 1024;
    bf16* Wbq = Xbv + (size_t)4096 * 1024;
    bf16* Wbk = Wbq + (size_t)1024 * 1024;
    bf16* Wbv = Wbk + (size_t)1024 * 1024;

    cvt_kernel<<<dim3(1024, 6), 256, 0, stream>>>(
        q, k, v, Wq, Wk, Wv, Xbq, Xbk, Xbv, Wbq, Wbk, Wbv);
    proj_kernel<<<dim3(8, 32, 3), 256, 0, stream>>>(
        Xbq, Xbk, Xbv, Wbq, Wbk, Wbv, bq, bk, bv, Qp, Kp, Vt);
    attn_kernel<<<dim3(512, 1, 1), 256, 0, stream>>>(
        Qp, Kp, Vt, mask, ctx, scores);
}